// Round 1
// baseline (1220.556 us; speedup 1.0000x reference)
//
#include <hip/hip_runtime.h>
#include <hip/hip_bf16.h>
#include <math.h>

// ---------------------------------------------------------------------------
// Net: x(B,3,28,28) -> _cor (ch2 自-correlated with its 11x11 center) -> B,1,28,28
//      conv1 5x5 VALID (32) + relu + maxpool2 -> B,32,12,12
//      conv2 5x5 VALID (64) + relu + maxpool2 -> B,64,4,4
//      conv3 3x3 VALID (10) + relu + mean(hw) + log_softmax -> B,10
// fp32 throughout (no fp32 MFMA on CDNA4 -> VALU-bound, ~63 GFLOP total)
// ---------------------------------------------------------------------------

#define B_STRIDE 2352   // 3*28*28
#define CHW 784         // 28*28

// ============================ Kernel 1 =====================================
// fused cor + conv1 + relu + maxpool2. One block (384 thr) per image.
__global__ __launch_bounds__(384) void k1_cor_conv1_pool(
    const float* __restrict__ x, const float* __restrict__ w1,
    const float* __restrict__ b1, float* __restrict__ out1)
{
    __shared__ float ch[784];
    __shared__ float cor[784];
    __shared__ float w1s[800];
    __shared__ float b1s[32];

    const int b = blockIdx.x;
    const int tid = threadIdx.x;
    const float* xb = x + (size_t)b * B_STRIDE + 2 * CHW;

    for (int i = tid; i < 196; i += 384)
        ((float4*)ch)[i] = ((const float4*)xb)[i];
    for (int i = tid; i < 800; i += 384)
        w1s[i] = w1[i];
    if (tid < 32) b1s[tid] = b1[tid];
    __syncthreads();

    // ---- cor: out 28x28, pad 5, kernel = ch[8:19,8:19] (11x11), no flip ----
    // 196 threads, each computes 4 contiguous outputs of one row.
    if (tid < 196) {
        const int y = tid / 7;          // 0..27
        const int x0 = (tid % 7) * 4;   // 0,4,...,24
        float a0 = 0.f, a1 = 0.f, a2 = 0.f, a3 = 0.f;
        for (int ky = 0; ky < 11; ++ky) {
            const int iy = y - 5 + ky;
            if (iy < 0 || iy >= 28) continue;
            const float* trow = &ch[(8 + ky) * 28 + 8]; // template row
            const float* irow = &ch[iy * 28];
            float in[14];
#pragma unroll
            for (int c = 0; c < 14; ++c) {
                const int ix = x0 - 5 + c;
                in[c] = (ix >= 0 && ix < 28) ? irow[ix] : 0.f;
            }
#pragma unroll
            for (int kx = 0; kx < 11; ++kx) {
                const float w = trow[kx];
                a0 = fmaf(in[kx + 0], w, a0);
                a1 = fmaf(in[kx + 1], w, a1);
                a2 = fmaf(in[kx + 2], w, a2);
                a3 = fmaf(in[kx + 3], w, a3);
            }
        }
        cor[y * 28 + x0 + 0] = a0;
        cor[y * 28 + x0 + 1] = a1;
        cor[y * 28 + x0 + 2] = a2;
        cor[y * 28 + x0 + 3] = a3;
    }
    __syncthreads();

    // ---- conv1 5x5 VALID -> 24x24, relu, pool -> 12x12 ----
    // thread = (oc = tid&31, py = tid>>5 in 0..11); computes conv rows 2py,2py+1
    // (sliding over 6 input rows), pools to one 12-wide output row.
    const int oc = tid & 31;
    const int py = tid >> 5;
    float acc0[24], acc1[24];
#pragma unroll
    for (int i = 0; i < 24; ++i) { acc0[i] = 0.f; acc1[i] = 0.f; }
    const float* wrow = &w1s[oc * 25];
#pragma unroll
    for (int r = 0; r < 6; ++r) {
        float row[28];
        const float4* srow = (const float4*)&cor[(2 * py + r) * 28];
#pragma unroll
        for (int i = 0; i < 7; ++i) ((float4*)row)[i] = srow[i];
        if (r < 5) {
#pragma unroll
            for (int kx = 0; kx < 5; ++kx) {
                const float w = wrow[r * 5 + kx];
#pragma unroll
                for (int xo = 0; xo < 24; ++xo)
                    acc0[xo] = fmaf(row[xo + kx], w, acc0[xo]);
            }
        }
        if (r >= 1) {
#pragma unroll
            for (int kx = 0; kx < 5; ++kx) {
                const float w = wrow[(r - 1) * 5 + kx];
#pragma unroll
                for (int xo = 0; xo < 24; ++xo)
                    acc1[xo] = fmaf(row[xo + kx], w, acc1[xo]);
            }
        }
    }
    const float bias = b1s[oc];
    float pooled[12];
#pragma unroll
    for (int px = 0; px < 12; ++px) {
        const float m = fmaxf(fmaxf(acc0[2 * px], acc0[2 * px + 1]),
                              fmaxf(acc1[2 * px], acc1[2 * px + 1]));
        pooled[px] = fmaxf(m + bias, 0.f);   // relu(max) == max(relu)
    }
    float* dst = out1 + (size_t)b * 4608 + oc * 144 + py * 12;
#pragma unroll
    for (int i = 0; i < 3; ++i)
        ((float4*)dst)[i] = ((float4*)pooled)[i];
}

// ============================ Kernel 2 =====================================
// conv2 5x5 VALID (32->64ch) + relu + maxpool2. One block (256 thr) per image.
// Weights staged in LDS transposed to [r][oc] with stride 65 (bank-conflict-free
// both on the staging writes and the stride-1-per-lane inner reads).
#define IC_CHUNK 4
__global__ __launch_bounds__(256) void k2_conv2_pool(
    const float* __restrict__ in1, const float* __restrict__ w2,
    const float* __restrict__ b2, float* __restrict__ out2)
{
    __shared__ float xin[4608];                 // [ic][12][12]
    __shared__ float ws[IC_CHUNK * 25 * 65];    // [icl*25+k][oc], padded 65
    __shared__ float b2s[64];

    const int b = blockIdx.x;
    const int tid = threadIdx.x;
    const float* src = in1 + (size_t)b * 4608;
    for (int i = tid; i < 1152; i += 256)
        ((float4*)xin)[i] = ((const float4*)src)[i];
    if (tid < 64) b2s[tid] = b2[tid];

    const int oc = tid & 31;   // handles oc and oc+32
    const int oy = tid >> 5;   // 0..7 (conv output row)
    float acc0[8], acc1[8];
#pragma unroll
    for (int i = 0; i < 8; ++i) { acc0[i] = 0.f; acc1[i] = 0.f; }

    for (int icc = 0; icc < 32 / IC_CHUNK; ++icc) {
        __syncthreads();   // protect ws reuse (and xin on first pass)
        for (int i = tid; i < 64 * IC_CHUNK * 25; i += 256) {
            const int ocw = i / (IC_CHUNK * 25);
            const int r = i - ocw * (IC_CHUNK * 25);
            ws[r * 65 + ocw] = w2[ocw * 800 + icc * (IC_CHUNK * 25) + r];
        }
        __syncthreads();
#pragma unroll
        for (int icl = 0; icl < IC_CHUNK; ++icl) {
            const float* xbase = &xin[(icc * IC_CHUNK + icl) * 144];
#pragma unroll
            for (int ky = 0; ky < 5; ++ky) {
                float row[12];
                const float4* rsrc = (const float4*)(xbase + (oy + ky) * 12);
#pragma unroll
                for (int i = 0; i < 3; ++i) ((float4*)row)[i] = rsrc[i];
                const float* wr = &ws[(icl * 25 + ky * 5) * 65 + oc];
#pragma unroll
                for (int kx = 0; kx < 5; ++kx) {
                    const float w0 = wr[kx * 65];
                    const float w1v = wr[kx * 65 + 32];
#pragma unroll
                    for (int ox = 0; ox < 8; ++ox) {
                        acc0[ox] = fmaf(row[ox + kx], w0, acc0[ox]);
                        acc1[ox] = fmaf(row[ox + kx], w1v, acc1[ox]);
                    }
                }
            }
        }
    }
    const float bi0 = b2s[oc], bi1 = b2s[oc + 32];
    float v0[8], v1[8];
#pragma unroll
    for (int i = 0; i < 8; ++i) {
        v0[i] = fmaxf(acc0[i] + bi0, 0.f);
        v1[i] = fmaxf(acc1[i] + bi1, 0.f);
    }
    // vertical pool: partner row lives in lane^32 (oy pairs within a wave)
#pragma unroll
    for (int i = 0; i < 8; ++i) {
        const float o0 = __shfl_xor(v0[i], 32);
        const float o1 = __shfl_xor(v1[i], 32);
        v0[i] = fmaxf(v0[i], o0);
        v1[i] = fmaxf(v1[i], o1);
    }
    float p0[4], p1[4];
#pragma unroll
    for (int i = 0; i < 4; ++i) {
        p0[i] = fmaxf(v0[2 * i], v0[2 * i + 1]);
        p1[i] = fmaxf(v1[2 * i], v1[2 * i + 1]);
    }
    if ((oy & 1) == 0) {
        const int pyy = oy >> 1;
        float* dst = out2 + (size_t)b * 1024 + oc * 16 + pyy * 4;
        *((float4*)dst) = make_float4(p0[0], p0[1], p0[2], p0[3]);
        *((float4*)(dst + 512)) = make_float4(p1[0], p1[1], p1[2], p1[3]);
    }
}

// ============================ Kernel 3 =====================================
// conv3 3x3 VALID (64->10) + relu + spatial mean + log_softmax.
// One wave per image, 4 images per block.
__global__ __launch_bounds__(256) void k3_conv3_head(
    const float* __restrict__ in2, const float* __restrict__ w3,
    const float* __restrict__ b3, float* __restrict__ out)
{
    __shared__ float w3s[10 * 577];   // padded stride 577 (576 is bank-aligned)
    __shared__ float b3s[10];
    __shared__ float xin[4 * 1024];
    __shared__ float lg[4][16];

    const int tid = threadIdx.x;
    const int b0 = blockIdx.x * 4;

    for (int i = tid; i < 5760; i += 256)
        w3s[(i / 576) * 577 + (i % 576)] = w3[i];
    if (tid < 10) b3s[tid] = b3[tid];
    const float* src = in2 + (size_t)b0 * 1024;
    for (int i = tid; i < 1024; i += 256)
        ((float4*)xin)[i] = ((const float4*)src)[i];
    __syncthreads();

    const int img = tid >> 6;    // wave id = image
    const int lane = tid & 63;
    const int oc = lane >> 2;    // 0..15, valid < 10
    const int pos = lane & 3;    // spatial position (2x2)
    float v = 0.f;
    if (oc < 10) {
        const int oy = pos >> 1, ox = pos & 1;
        const float* xi = &xin[img * 1024 + oy * 4 + ox];
        const float* wr = &w3s[oc * 577];
        float a = 0.f;
        for (int ic = 0; ic < 64; ++ic) {
            const float* xc = xi + ic * 16;
            const float* wc = wr + ic * 9;
#pragma unroll
            for (int ky = 0; ky < 3; ++ky)
#pragma unroll
                for (int kx = 0; kx < 3; ++kx)
                    a = fmaf(xc[ky * 4 + kx], wc[ky * 3 + kx], a);
        }
        v = fmaxf(a + b3s[oc], 0.f);
    }
    // mean over the 4 spatial lanes of this oc
    v += __shfl_xor(v, 1);
    v += __shfl_xor(v, 2);
    v *= 0.25f;
    if (pos == 0 && oc < 10) lg[img][oc] = v;
    __syncthreads();
    if (lane == 0) {
        float mx = -1e30f;
        for (int i = 0; i < 10; ++i) mx = fmaxf(mx, lg[img][i]);
        float s = 0.f;
        for (int i = 0; i < 10; ++i) s += expf(lg[img][i] - mx);
        const float lse = mx + logf(s);
        float* o = out + (size_t)(b0 + img) * 10;
        for (int i = 0; i < 10; ++i) o[i] = lg[img][i] - lse;
    }
}

// ============================ Launch =======================================
extern "C" void kernel_launch(void* const* d_in, const int* in_sizes, int n_in,
                              void* d_out, int out_size, void* d_ws, size_t ws_size,
                              hipStream_t stream)
{
    const float* x  = (const float*)d_in[0];
    const float* w1 = (const float*)d_in[1];
    const float* b1 = (const float*)d_in[2];
    const float* w2 = (const float*)d_in[3];
    const float* b2 = (const float*)d_in[4];
    const float* w3 = (const float*)d_in[5];
    const float* b3 = (const float*)d_in[6];
    float* out = (float*)d_out;

    const int B = in_sizes[0] / B_STRIDE;          // 8192
    float* pool1 = (float*)d_ws;                   // B*4608 f32 (~151 MB)
    float* pool2 = pool1 + (size_t)B * 4608;       // B*1024 f32 (~34 MB)

    k1_cor_conv1_pool<<<B, 384, 0, stream>>>(x, w1, b1, pool1);
    k2_conv2_pool<<<B, 256, 0, stream>>>(pool1, w2, b2, pool2);
    k3_conv3_head<<<B / 4, 256, 0, stream>>>(pool2, w3, b3, out);
}

// Round 2
// 511.435 us; speedup vs baseline: 2.3865x; 2.3865x over previous
//
#include <hip/hip_runtime.h>
#include <hip/hip_bf16.h>
#include <math.h>

// ---------------------------------------------------------------------------
// Net: x(B,3,28,28) -> _cor (ch2 correlated with its 11x11 center) -> B,1,28,28
//      conv1 5x5 VALID (32) + relu + maxpool2 -> B,32,12,12
//      conv2 5x5 VALID (64) + relu + maxpool2 -> B,64,4,4   [MFMA fp16]
//      conv3 3x3 VALID (10) + relu + mean(hw) + log_softmax -> B,10
// ---------------------------------------------------------------------------

#define B_STRIDE 2352   // 3*28*28
#define CHW 784         // 28*28

typedef _Float16 f16x8 __attribute__((ext_vector_type(8)));
typedef _Float16 f16x2 __attribute__((ext_vector_type(2)));
typedef float f32x4 __attribute__((ext_vector_type(4)));

// ============================ Kernel 1 =====================================
// fused cor + conv1 + relu + maxpool2. One block (384 thr) per image.
__global__ __launch_bounds__(384) void k1_cor_conv1_pool(
    const float* __restrict__ x, const float* __restrict__ w1,
    const float* __restrict__ b1, float* __restrict__ out1)
{
    __shared__ float ch[784];
    __shared__ float cor[784];
    __shared__ float w1s[800];
    __shared__ float b1s[32];

    const int b = blockIdx.x;
    const int tid = threadIdx.x;
    const float* xb = x + (size_t)b * B_STRIDE + 2 * CHW;

    for (int i = tid; i < 196; i += 384)
        ((float4*)ch)[i] = ((const float4*)xb)[i];
    for (int i = tid; i < 800; i += 384)
        w1s[i] = w1[i];
    if (tid < 32) b1s[tid] = b1[tid];
    __syncthreads();

    // ---- cor: out 28x28, pad 5, kernel = ch[8:19,8:19] (11x11), no flip ----
    if (tid < 196) {
        const int y = tid / 7;          // 0..27
        const int x0 = (tid % 7) * 4;   // 0,4,...,24
        float a0 = 0.f, a1 = 0.f, a2 = 0.f, a3 = 0.f;
        for (int ky = 0; ky < 11; ++ky) {
            const int iy = y - 5 + ky;
            if (iy < 0 || iy >= 28) continue;
            const float* trow = &ch[(8 + ky) * 28 + 8]; // template row
            const float* irow = &ch[iy * 28];
            float in[14];
#pragma unroll
            for (int c = 0; c < 14; ++c) {
                const int ix = x0 - 5 + c;
                in[c] = (ix >= 0 && ix < 28) ? irow[ix] : 0.f;
            }
#pragma unroll
            for (int kx = 0; kx < 11; ++kx) {
                const float w = trow[kx];
                a0 = fmaf(in[kx + 0], w, a0);
                a1 = fmaf(in[kx + 1], w, a1);
                a2 = fmaf(in[kx + 2], w, a2);
                a3 = fmaf(in[kx + 3], w, a3);
            }
        }
        cor[y * 28 + x0 + 0] = a0;
        cor[y * 28 + x0 + 1] = a1;
        cor[y * 28 + x0 + 2] = a2;
        cor[y * 28 + x0 + 3] = a3;
    }
    __syncthreads();

    // ---- conv1 5x5 VALID -> 24x24, relu, pool -> 12x12 ----
    const int oc = tid & 31;
    const int py = tid >> 5;
    float acc0[24], acc1[24];
#pragma unroll
    for (int i = 0; i < 24; ++i) { acc0[i] = 0.f; acc1[i] = 0.f; }
    const float* wrow = &w1s[oc * 25];
#pragma unroll
    for (int r = 0; r < 6; ++r) {
        float row[28];
        const float4* srow = (const float4*)&cor[(2 * py + r) * 28];
#pragma unroll
        for (int i = 0; i < 7; ++i) ((float4*)row)[i] = srow[i];
        if (r < 5) {
#pragma unroll
            for (int kx = 0; kx < 5; ++kx) {
                const float w = wrow[r * 5 + kx];
#pragma unroll
                for (int xo = 0; xo < 24; ++xo)
                    acc0[xo] = fmaf(row[xo + kx], w, acc0[xo]);
            }
        }
        if (r >= 1) {
#pragma unroll
            for (int kx = 0; kx < 5; ++kx) {
                const float w = wrow[(r - 1) * 5 + kx];
#pragma unroll
                for (int xo = 0; xo < 24; ++xo)
                    acc1[xo] = fmaf(row[xo + kx], w, acc1[xo]);
            }
        }
    }
    const float bias = b1s[oc];
    float pooled[12];
#pragma unroll
    for (int px = 0; px < 12; ++px) {
        const float m = fmaxf(fmaxf(acc0[2 * px], acc0[2 * px + 1]),
                              fmaxf(acc1[2 * px], acc1[2 * px + 1]));
        pooled[px] = fmaxf(m + bias, 0.f);   // relu(max) == max(relu)
    }
    float* dst = out1 + (size_t)b * 4608 + oc * 144 + py * 12;
#pragma unroll
    for (int i = 0; i < 3; ++i)
        ((float4*)dst)[i] = ((float4*)pooled)[i];
}

// ============================ Kernel 2 (MFMA fp16) =========================
// conv2 5x5 VALID (32->64) + relu + maxpool2 via mfma_f32_16x16x32_f16.
// One block (4 waves) per CU; each wave does one image per round.
// Per (ky,kx): GEMM 64oc x 64pos x 32ic = 16 MFMAs, acc in fp32.
#define K2_ROUNDS 8
__global__ __launch_bounds__(256, 1) void k2_conv2_pool_mfma(
    const float* __restrict__ in1, const float* __restrict__ w2,
    const float* __restrict__ b2, float* __restrict__ out2)
{
    // frag-linear A: [kpos][ocg][lane][8 halves] -> lane reads 16B at base+lane*16
    __shared__ __align__(16) _Float16 AW[25 * 4 * 64 * 8];   // 100 KB
    // per-wave B: [icg][pos][8ic] fp16, pos = y*12+x (ic-contiguous for b128)
    __shared__ __align__(16) _Float16 XT[4][4 * 144 * 8];    // 4 x 9 KB
    __shared__ float b2s[64];

    const int tid = threadIdx.x;
    const int wave = tid >> 6;
    const int lane = tid & 63;

    // ---- stage weights once per block: w2[oc][ic][ky][kx] fp32 -> AW fp16 ----
    for (int it = 0; it < 100; ++it) {
        const int flat = it * 256 + tid;             // (oc*16+icp)*25 + kpos
        const int rest = (flat * 5243) >> 17;        // flat / 25 (exact for <25600)
        const int kpos = flat - rest * 25;
        const int oc = rest >> 4, icp = rest & 15;   // icp = ic pair index
        const float* g = w2 + oc * 800 + icp * 50 + kpos;
        f16x2 v = { (_Float16)g[0], (_Float16)g[25] };
        const int lane_w = (oc & 15) + (icp >> 2) * 16;
        const int idx = (((kpos * 4 + (oc >> 4)) * 64) + lane_w) * 8 + (icp & 3) * 2;
        *(f16x2*)&AW[idx] = v;
    }
    if (tid < 64) b2s[tid] = b2[tid];

    const int b0 = blockIdx.x * (4 * K2_ROUNDS);
    const int hi = (lane >> 3) & 1;     // within-tile row half
    const int ox = lane & 7;            // conv output col
    const int icg = lane >> 4;          // ic group for B frag
    _Float16* xtw = &XT[wave][0];

    for (int r = 0; r < K2_ROUNDS; ++r) {
        __syncthreads();   // WAR on xtw across rounds; first iter: AW visible
        const int img = b0 + r * 4 + wave;

        // ---- stage xt (per wave, own image): [ic][144] f32 -> [icg][pos][8] f16
        const float* src = in1 + (size_t)img * 4608;
        for (int pos = lane; pos < 144; pos += 64) {
#pragma unroll
            for (int icp = 0; icp < 16; ++icp) {
                const float a0 = src[(2 * icp) * 144 + pos];
                const float a1 = src[(2 * icp + 1) * 144 + pos];
                f16x2 v = { (_Float16)a0, (_Float16)a1 };
                *(f16x2*)&xtw[((icp >> 2) * 144 + pos) * 8 + (icp & 3) * 2] = v;
            }
        }
        __syncthreads();

        f32x4 acc[4][4];
#pragma unroll
        for (int i = 0; i < 4; ++i)
#pragma unroll
            for (int j = 0; j < 4; ++j)
                acc[i][j] = (f32x4){0.f, 0.f, 0.f, 0.f};

        const int prow = hi * 12 + ox;   // lane-local spatial base (pos units)
#pragma unroll
        for (int kpos = 0; kpos < 25; ++kpos) {
            const int ky = kpos / 5, kx = kpos % 5;
            f16x8 af[4], bf[4];
#pragma unroll
            for (int i = 0; i < 4; ++i)
                af[i] = *(const f16x8*)&AW[(((kpos * 4 + i) * 64) + lane) * 8];
#pragma unroll
            for (int j = 0; j < 4; ++j) {
                const int p = prow + (2 * j + ky) * 12 + kx;
                bf[j] = *(const f16x8*)&xtw[(icg * 144 + p) * 8];
            }
#pragma unroll
            for (int i = 0; i < 4; ++i)
#pragma unroll
                for (int j = 0; j < 4; ++j)
                    acc[i][j] = __builtin_amdgcn_mfma_f32_16x16x32_f16(
                        af[i], bf[j], acc[i][j], 0, 0, 0);
        }

        // ---- epilogue: bias + relu + 2x2 pool + write [64][4][4] ----
        // D layout: oc = i*16 + (lane>>4)*4 + rr ; pos = j*16 + (lane&15)
        // pool partners: horizontal lane^1, vertical lane^8; py == j.
        float* dst = out2 + (size_t)img * 1024;
#pragma unroll
        for (int i = 0; i < 4; ++i)
#pragma unroll
            for (int j = 0; j < 4; ++j)
#pragma unroll
                for (int rr = 0; rr < 4; ++rr) {
                    const int oc = i * 16 + (lane >> 4) * 4 + rr;
                    float v = fmaxf(acc[i][j][rr] + b2s[oc], 0.f);
                    v = fmaxf(v, __shfl_xor(v, 1));
                    v = fmaxf(v, __shfl_xor(v, 8));
                    if ((lane & 9) == 0)
                        dst[oc * 16 + j * 4 + (ox >> 1)] = v;
                }
    }
}

// ============================ Kernel 3 =====================================
// conv3 3x3 VALID (64->10) + relu + spatial mean + log_softmax.
__global__ __launch_bounds__(256) void k3_conv3_head(
    const float* __restrict__ in2, const float* __restrict__ w3,
    const float* __restrict__ b3, float* __restrict__ out)
{
    __shared__ float w3s[10 * 577];   // padded stride 577
    __shared__ float b3s[10];
    __shared__ float xin[4 * 1024];
    __shared__ float lg[4][16];

    const int tid = threadIdx.x;
    const int b0 = blockIdx.x * 4;

    for (int i = tid; i < 5760; i += 256)
        w3s[(i / 576) * 577 + (i % 576)] = w3[i];
    if (tid < 10) b3s[tid] = b3[tid];
    const float* src = in2 + (size_t)b0 * 1024;
    for (int i = tid; i < 1024; i += 256)
        ((float4*)xin)[i] = ((const float4*)src)[i];
    __syncthreads();

    const int img = tid >> 6;
    const int lane = tid & 63;
    const int oc = lane >> 2;
    const int pos = lane & 3;
    float v = 0.f;
    if (oc < 10) {
        const int oy = pos >> 1, oxx = pos & 1;
        const float* xi = &xin[img * 1024 + oy * 4 + oxx];
        const float* wr = &w3s[oc * 577];
        float a = 0.f;
        for (int ic = 0; ic < 64; ++ic) {
            const float* xc = xi + ic * 16;
            const float* wc = wr + ic * 9;
#pragma unroll
            for (int ky = 0; ky < 3; ++ky)
#pragma unroll
                for (int kx = 0; kx < 3; ++kx)
                    a = fmaf(xc[ky * 4 + kx], wc[ky * 3 + kx], a);
        }
        v = fmaxf(a + b3s[oc], 0.f);
    }
    v += __shfl_xor(v, 1);
    v += __shfl_xor(v, 2);
    v *= 0.25f;
    if (pos == 0 && oc < 10) lg[img][oc] = v;
    __syncthreads();
    if (lane == 0) {
        float mx = -1e30f;
        for (int i = 0; i < 10; ++i) mx = fmaxf(mx, lg[img][i]);
        float s = 0.f;
        for (int i = 0; i < 10; ++i) s += expf(lg[img][i] - mx);
        const float lse = mx + logf(s);
        float* o = out + (size_t)(b0 + img) * 10;
        for (int i = 0; i < 10; ++i) o[i] = lg[img][i] - lse;
    }
}

// ============================ Launch =======================================
extern "C" void kernel_launch(void* const* d_in, const int* in_sizes, int n_in,
                              void* d_out, int out_size, void* d_ws, size_t ws_size,
                              hipStream_t stream)
{
    const float* x  = (const float*)d_in[0];
    const float* w1 = (const float*)d_in[1];
    const float* b1 = (const float*)d_in[2];
    const float* w2 = (const float*)d_in[3];
    const float* b2 = (const float*)d_in[4];
    const float* w3 = (const float*)d_in[5];
    const float* b3 = (const float*)d_in[6];
    float* out = (float*)d_out;

    const int B = in_sizes[0] / B_STRIDE;          // 8192
    float* pool1 = (float*)d_ws;                   // B*4608 f32
    float* pool2 = pool1 + (size_t)B * 4608;       // B*1024 f32

    k1_cor_conv1_pool<<<B, 384, 0, stream>>>(x, w1, b1, pool1);
    k2_conv2_pool_mfma<<<B / (4 * K2_ROUNDS), 256, 0, stream>>>(pool1, w2, b2, pool2);
    k3_conv3_head<<<B / 4, 256, 0, stream>>>(pool2, w3, b3, out);
}

// Round 3
// 298.731 us; speedup vs baseline: 4.0858x; 1.7120x over previous
//
#include <hip/hip_runtime.h>
#include <hip/hip_bf16.h>
#include <math.h>

// ---------------------------------------------------------------------------
// Net: x(B,3,28,28) -> _cor (ch2 correlated with its 11x11 center) -> B,1,28,28
//      conv1 5x5 VALID (32) + relu + maxpool2 -> B,32,12,12   [MFMA fp16]
//      conv2 5x5 VALID (64) + relu + maxpool2 -> B,64,4,4     [MFMA fp16]
//      conv3 3x3 VALID (10) + relu + mean(hw) + log_softmax -> B,10
// Intermediate pool1 stored fp16 [img][144 pos][32 ic] (same rounding point
// as before: k2 always consumed conv1 output through fp16).
// ---------------------------------------------------------------------------

#define B_STRIDE 2352   // 3*28*28

typedef _Float16 f16x8 __attribute__((ext_vector_type(8)));
typedef _Float16 f16x4 __attribute__((ext_vector_type(4)));
typedef _Float16 f16x2 __attribute__((ext_vector_type(2)));
typedef float f32x4 __attribute__((ext_vector_type(4)));

// ============================ Kernel 1 =====================================
// fused cor + conv1(MFMA) + relu + maxpool2. 512 thr = 8 waves; 1 img/wave,
// 2 rounds. Wave-local phases only (no block barriers in the loop).
#define K1_WAVES 8
#define K1_ROUNDS 2
__global__ __launch_bounds__(512, 4) void k1_cor_conv1_pool(
    const float* __restrict__ x, const float* __restrict__ w1,
    const float* __restrict__ b1, _Float16* __restrict__ out1h)
{
    __shared__ float PAD[K1_WAVES][1444];     // 38x38 zero-padded ch
    __shared__ float COR[K1_WAVES][784];      // 28x28 cor output (fp32)
    __shared__ _Float16 AW1[2 * 64 * 8];      // conv1 A-frags, 2 oc-tiles
    __shared__ float b1s[32];

    const int tid = threadIdx.x;
    const int wave = tid >> 6;
    const int lane = tid & 63;

    // ---- stage conv1 A-frags: A[oc][k=tap], taps 25..31 zeroed ----
    for (int e = tid; e < 1024; e += 512) {
        const int ln = (e >> 3) & 63;
        const int oc = ((e >> 9) << 4) + (ln & 15);
        const int k = ((ln >> 4) << 3) + (e & 7);
        AW1[e] = (k < 25) ? (_Float16)w1[oc * 25 + k] : (_Float16)0.f;
    }
    if (tid < 32) b1s[tid] = b1[tid];
    __syncthreads();

    // per-lane constants
    const int g = lane >> 4;        // MFMA k-group / oc-subrow
    const int c = lane & 15;        // MFMA column
    int off[8];
#pragma unroll
    for (int jj = 0; jj < 8; ++jj) {
        const int k = g * 8 + jj;
        const int ky = k / 5;
        off[jj] = (k < 25) ? (ky * 28 + (k - ky * 5)) : 0;
    }
    const f16x8 af0 = *(const f16x8*)&AW1[lane * 8];
    const f16x8 af1 = *(const f16x8*)&AW1[(64 + lane) * 8];
    float bia0[4], bia1[4];
#pragma unroll
    for (int rr = 0; rr < 4; ++rr) {
        bia0[rr] = b1s[g * 4 + rr];
        bia1[rr] = b1s[16 + g * 4 + rr];
    }
    const int yy = lane >> 1;       // cor row (valid < 28)
    const int x0 = (lane & 1) * 14; // cor col base
    float* padw = &PAD[wave][0];
    float* corw = &COR[wave][0];

    for (int r = 0; r < K1_ROUNDS; ++r) {
        const int img = blockIdx.x * (K1_WAVES * K1_ROUNDS) + r * K1_WAVES + wave;

        // ---- zero pad buffer, then fill interior with ch2 ----
        for (int i = lane; i < 361; i += 64)
            ((f32x4*)padw)[i] = (f32x4){0.f, 0.f, 0.f, 0.f};
        const float* xb = x + (size_t)img * B_STRIDE + 1568;  // channel 2
        for (int i = lane; i < 196; i += 64) {
            const float4 v = ((const float4*)xb)[i];
            const int yv = i / 7;             // (i*4)/28 exact
            float* d = &padw[(5 + yv) * 38 + 5 + (i - yv * 7) * 4];
            d[0] = v.x; d[1] = v.y; d[2] = v.z; d[3] = v.w;
        }

        // ---- cor: 56 lanes, one 14-wide half-row each ----
        if (yy < 28) {
            float a[14];
#pragma unroll
            for (int t = 0; t < 14; ++t) a[t] = 0.f;
#pragma unroll
            for (int ky = 0; ky < 11; ++ky) {
                const float* prow = &padw[(yy + ky) * 38 + x0];
                float rr2[24];
#pragma unroll
                for (int t2 = 0; t2 < 12; ++t2) {
                    const float2 v2 = ((const float2*)prow)[t2];
                    rr2[2 * t2] = v2.x; rr2[2 * t2 + 1] = v2.y;
                }
                const float* trow = &padw[(13 + ky) * 38 + 13];
#pragma unroll
                for (int kx = 0; kx < 11; ++kx) {
                    const float w = trow[kx];   // broadcast
#pragma unroll
                    for (int t = 0; t < 14; ++t)
                        a[t] = fmaf(rr2[kx + t], w, a[t]);
                }
            }
            float* cw = &corw[yy * 28 + x0];
#pragma unroll
            for (int t2 = 0; t2 < 7; ++t2) {
                const float2 v2 = {a[2 * t2], a[2 * t2 + 1]};
                ((float2*)cw)[t2] = v2;
            }
        }

        // ---- conv1 via MFMA: N ordered q-major so pool is in-lane ----
        // pp = jq*16 + c (pool window 0..143), q = pool quadrant.
        _Float16* outw = out1h + (size_t)img * 4608;
#pragma unroll
        for (int jq = 0; jq < 9; ++jq) {
            const int pp = jq * 16 + c;
            const int py = pp / 12, px = pp - py * 12;
            f32x4 pm0, pm1;
#pragma unroll
            for (int q = 0; q < 4; ++q) {
                const int base = (2 * py + (q >> 1)) * 28 + 2 * px + (q & 1);
                f16x8 bf;
#pragma unroll
                for (int jj = 0; jj < 8; ++jj)
                    bf[jj] = (_Float16)corw[base + off[jj]];
                const f32x4 z = {0.f, 0.f, 0.f, 0.f};
                const f32x4 d0 = __builtin_amdgcn_mfma_f32_16x16x32_f16(af0, bf, z, 0, 0, 0);
                const f32x4 d1 = __builtin_amdgcn_mfma_f32_16x16x32_f16(af1, bf, z, 0, 0, 0);
                if (q == 0) { pm0 = d0; pm1 = d1; }
                else {
#pragma unroll
                    for (int rr = 0; rr < 4; ++rr) {
                        pm0[rr] = fmaxf(pm0[rr], d0[rr]);
                        pm1[rr] = fmaxf(pm1[rr], d1[rr]);
                    }
                }
            }
            f16x4 s0, s1;
#pragma unroll
            for (int rr = 0; rr < 4; ++rr) {
                s0[rr] = (_Float16)fmaxf(pm0[rr] + bia0[rr], 0.f);
                s1[rr] = (_Float16)fmaxf(pm1[rr] + bia1[rr], 0.f);
            }
            _Float16* dsth = outw + pp * 32 + g * 4;
            *(f16x4*)dsth = s0;          // oc 0..15 tile
            *(f16x4*)(dsth + 16) = s1;   // oc 16..31 tile
        }
    }
}

// ============================ Kernel 2 (MFMA fp16) =========================
// conv2 5x5 VALID (32->64) + relu + maxpool2. 512 thr = 8 waves; 2 waves
// share one image (each does 2 of 4 j-tiles) -> 4 img/round, 8 rounds.
#define K2_ROUNDS 8
__global__ __launch_bounds__(512, 2) void k2_conv2_pool_mfma(
    const _Float16* __restrict__ in1h, const float* __restrict__ w2,
    const float* __restrict__ b2, float* __restrict__ out2)
{
    __shared__ __align__(16) _Float16 AW[25 * 4 * 64 * 8];   // 100 KB
    __shared__ __align__(16) _Float16 XT[4][4 * 144 * 8];    // 36 KB
    __shared__ float b2s[64];

    const int tid = threadIdx.x;
    const int wave = tid >> 6;
    const int lane = tid & 63;
    const int widx = wave >> 1;     // image slot 0..3
    const int half = wave & 1;      // j-tile half
    const int jb = half * 2;

    // ---- stage weights once per block ----
    for (int it = 0; it < 50; ++it) {
        const int flat = it * 512 + tid;             // (oc*16+icp)*25 + kpos
        const int rest = (flat * 5243) >> 17;        // flat / 25
        const int kpos = flat - rest * 25;
        const int oc = rest >> 4, icp = rest & 15;
        const float* gsrc = w2 + oc * 800 + icp * 50 + kpos;
        const f16x2 v = { (_Float16)gsrc[0], (_Float16)gsrc[25] };
        const int lane_w = (oc & 15) + (icp >> 2) * 16;
        const int idx = (((kpos * 4 + (oc >> 4)) * 64) + lane_w) * 8 + (icp & 3) * 2;
        *(f16x2*)&AW[idx] = v;
    }
    if (tid < 64) b2s[tid] = b2[tid];

    const int b0 = blockIdx.x * (4 * K2_ROUNDS);
    const int hi = (lane >> 3) & 1;
    const int ox = lane & 7;
    const int icg = lane >> 4;
    _Float16* xtw = &XT[widx][0];

    for (int r = 0; r < K2_ROUNDS; ++r) {
        __syncthreads();   // WAR on XT; first iter: AW visible
        const int img = b0 + r * 4 + widx;

        // ---- stage image (pair of waves): [pos][32ic] -> [icg][pos][8] ----
        const _Float16* srch = in1h + (size_t)img * 4608;
        for (int p = lane + half * 64; p < 144; p += 128) {
            const f16x8* s8 = (const f16x8*)(srch + p * 32);
#pragma unroll
            for (int ig = 0; ig < 4; ++ig)
                *(f16x8*)&xtw[(ig * 144 + p) * 8] = s8[ig];
        }
        __syncthreads();

        f32x4 acc[4][2];
#pragma unroll
        for (int i = 0; i < 4; ++i)
#pragma unroll
            for (int jj = 0; jj < 2; ++jj)
                acc[i][jj] = (f32x4){0.f, 0.f, 0.f, 0.f};

        const int prow = hi * 12 + ox;
#pragma unroll
        for (int kpos = 0; kpos < 25; ++kpos) {
            const int ky = kpos / 5, kx = kpos % 5;
            f16x8 af[4], bf[2];
#pragma unroll
            for (int i = 0; i < 4; ++i)
                af[i] = *(const f16x8*)&AW[(((kpos * 4 + i) * 64) + lane) * 8];
#pragma unroll
            for (int jj = 0; jj < 2; ++jj) {
                const int p = prow + (2 * (jb + jj) + ky) * 12 + kx;
                bf[jj] = *(const f16x8*)&xtw[(icg * 144 + p) * 8];
            }
#pragma unroll
            for (int i = 0; i < 4; ++i)
#pragma unroll
                for (int jj = 0; jj < 2; ++jj)
                    acc[i][jj] = __builtin_amdgcn_mfma_f32_16x16x32_f16(
                        af[i], bf[jj], acc[i][jj], 0, 0, 0);
        }

        // ---- epilogue: bias + relu + 2x2 pool + write [64][4][4] ----
        float* dst = out2 + (size_t)img * 1024;
#pragma unroll
        for (int i = 0; i < 4; ++i)
#pragma unroll
            for (int jj = 0; jj < 2; ++jj)
#pragma unroll
                for (int rr = 0; rr < 4; ++rr) {
                    const int oc = i * 16 + (lane >> 4) * 4 + rr;
                    float v = fmaxf(acc[i][jj][rr] + b2s[oc], 0.f);
                    v = fmaxf(v, __shfl_xor(v, 1));
                    v = fmaxf(v, __shfl_xor(v, 8));
                    if ((lane & 9) == 0)
                        dst[oc * 16 + (jb + jj) * 4 + (ox >> 1)] = v;
                }
    }
}

// ============================ Kernel 3 =====================================
// conv3 3x3 VALID (64->10) + relu + spatial mean + log_softmax.
__global__ __launch_bounds__(256) void k3_conv3_head(
    const float* __restrict__ in2, const float* __restrict__ w3,
    const float* __restrict__ b3, float* __restrict__ out)
{
    __shared__ float w3s[10 * 577];   // padded stride 577
    __shared__ float b3s[10];
    __shared__ float xin[4 * 1024];
    __shared__ float lg[4][16];

    const int tid = threadIdx.x;
    const int b0 = blockIdx.x * 4;

    for (int i = tid; i < 5760; i += 256)
        w3s[(i / 576) * 577 + (i % 576)] = w3[i];
    if (tid < 10) b3s[tid] = b3[tid];
    const float* src = in2 + (size_t)b0 * 1024;
    for (int i = tid; i < 1024; i += 256)
        ((float4*)xin)[i] = ((const float4*)src)[i];
    __syncthreads();

    const int img = tid >> 6;
    const int lane = tid & 63;
    const int oc = lane >> 2;
    const int pos = lane & 3;
    float v = 0.f;
    if (oc < 10) {
        const int oy = pos >> 1, oxx = pos & 1;
        const float* xi = &xin[img * 1024 + oy * 4 + oxx];
        const float* wr = &w3s[oc * 577];
        float a = 0.f;
        for (int ic = 0; ic < 64; ++ic) {
            const float* xc = xi + ic * 16;
            const float* wc = wr + ic * 9;
#pragma unroll
            for (int ky = 0; ky < 3; ++ky)
#pragma unroll
                for (int kx = 0; kx < 3; ++kx)
                    a = fmaf(xc[ky * 4 + kx], wc[ky * 3 + kx], a);
        }
        v = fmaxf(a + b3s[oc], 0.f);
    }
    v += __shfl_xor(v, 1);
    v += __shfl_xor(v, 2);
    v *= 0.25f;
    if (pos == 0 && oc < 10) lg[img][oc] = v;
    __syncthreads();
    if (lane == 0) {
        float mx = -1e30f;
        for (int i = 0; i < 10; ++i) mx = fmaxf(mx, lg[img][i]);
        float s = 0.f;
        for (int i = 0; i < 10; ++i) s += expf(lg[img][i] - mx);
        const float lse = mx + logf(s);
        float* o = out + (size_t)(b0 + img) * 10;
        for (int i = 0; i < 10; ++i) o[i] = lg[img][i] - lse;
    }
}

// ============================ Launch =======================================
extern "C" void kernel_launch(void* const* d_in, const int* in_sizes, int n_in,
                              void* d_out, int out_size, void* d_ws, size_t ws_size,
                              hipStream_t stream)
{
    const float* x  = (const float*)d_in[0];
    const float* w1 = (const float*)d_in[1];
    const float* b1 = (const float*)d_in[2];
    const float* w2 = (const float*)d_in[3];
    const float* b2 = (const float*)d_in[4];
    const float* w3 = (const float*)d_in[5];
    const float* b3 = (const float*)d_in[6];
    float* out = (float*)d_out;

    const int B = in_sizes[0] / B_STRIDE;                    // 8192
    _Float16* pool1h = (_Float16*)d_ws;                      // B*4608 f16 (~75 MB)
    float* pool2 = (float*)((char*)d_ws + (size_t)B * 4608 * 2);  // B*1024 f32

    k1_cor_conv1_pool<<<B / (K1_WAVES * K1_ROUNDS), 512, 0, stream>>>(x, w1, b1, pool1h);
    k2_conv2_pool_mfma<<<B / (4 * K2_ROUNDS), 512, 0, stream>>>(pool1h, w2, b2, pool2);
    k3_conv3_head<<<B / 4, 256, 0, stream>>>(pool2, w3, b3, out);
}